// Round 6
// baseline (317.295 us; speedup 1.0000x reference)
//
#include <hip/hip_runtime.h>

#define BATCH 32
#define ROWS 4   // source rows per frame-slot in the expand kernel

typedef float f32x4 __attribute__((ext_vector_type(4)));

// Kernel 1: per-row duration scan. Writes exclusive start offsets (B*S ints),
// totals (B ints), and total_lengths as float (output 1). No idxmap anymore.
__global__ void lr_scan_kernel(const float* __restrict__ dur,
                               const unsigned int* __restrict__ scale_raw,
                               float* __restrict__ out_tail,   // B floats (output 1)
                               int* __restrict__ totals,       // B ints (ws)
                               int* __restrict__ starts,       // B*S ints (ws)
                               int S) {
    __shared__ int partial[256];
    const int b = blockIdx.x;
    const int tid = threadIdx.x;

    // duration_scale dtype is ambiguous (python scalar). Normal floats have
    // exponent bits set => raw >= 0x00800000; small ints don't.
    unsigned int u = scale_raw[0];
    float scale = (u < 0x00800000u) ? (float)(int)u : __uint_as_float(u);

    const int PER = S / 256;            // 4 for S=1024
    int d[8];                           // supports S up to 2048
    int lsum = 0;
    const int base = tid * PER;
    for (int k = 0; k < PER; ++k) {
        float f = dur[b * S + base + k];
        int di = (int)(f * scale + 0.5f);   // trunc of non-negative == round-half-up
        if (di < 1) di = 1;
        d[k] = di;
        lsum += di;
    }
    partial[tid] = lsum;
    __syncthreads();

    // Hillis-Steele inclusive scan over 256 per-thread sums
    for (int off = 1; off < 256; off <<= 1) {
        int t = (tid >= off) ? partial[tid - off] : 0;
        __syncthreads();
        partial[tid] += t;
        __syncthreads();
    }

    int run = partial[tid] - lsum;      // exclusive prefix = start of this thread's span
    for (int k = 0; k < PER; ++k) {
        starts[b * S + base + k] = run;
        run += d[k];
    }

    if (tid == 255) {
        int total = partial[255];
        totals[b] = total;
        out_tail[b] = (float)total;     // output dtype for the flat buffer is f32
    }
}

// Kernel 2: expansion scatter. Each 128-lane slot owns ROWS consecutive source
// rows: load x row ONCE into registers, NT-store it d times to its output
// span. x read traffic = 67 MB (once), stores fully coalesced 2KB/frame.
// d is uniform across the slot's lanes -> no intra-wave divergence.
__global__ __launch_bounds__(256) void lr_expand_kernel(
        const f32x4* __restrict__ x4,
        const int* __restrict__ starts,
        const int* __restrict__ totals,
        f32x4* __restrict__ out4,
        int S, int T, int d4shift) {
    const int b = blockIdx.y;
    const int lane = threadIdx.x & ((1 << d4shift) - 1);   // 0..127
    const int slot = threadIdx.x >> d4shift;               // 0..spb-1
    const int spb = 256 >> d4shift;                        // 2
    const int s0 = (blockIdx.x * spb + slot) * ROWS;
    const int total = totals[b];                           // wave-uniform
    const int* srow = starts + b * S;
    const long long xbase = (((long long)b * S) << d4shift) + lane;
    const long long obase = (((long long)b * T) << d4shift) + lane;

    // Prefetch the ROWS x-rows and boundary offsets up front (independent loads).
    f32x4 v[ROWS];
    int st[ROWS + 1];
    #pragma unroll
    for (int k = 0; k < ROWS; ++k) {
        v[k] = x4[xbase + (((long long)(s0 + k)) << d4shift)];
        st[k] = srow[s0 + k];
    }
    st[ROWS] = (s0 + ROWS < S) ? srow[s0 + ROWS] : total;

    #pragma unroll
    for (int k = 0; k < ROWS; ++k) {
        for (int t = st[k]; t < st[k + 1]; ++t)
            __builtin_nontemporal_store(v[k], &out4[obase + (((long long)t) << d4shift)]);
    }
}

// Kernel 3: zero the tail frames [total[b], T). Worst-case grid, early exit.
__global__ __launch_bounds__(256) void lr_zero_tail_kernel(
        const int* __restrict__ totals,
        f32x4* __restrict__ out4,
        int T, int d4shift) {
    const int b = blockIdx.y;
    const int lane = threadIdx.x & ((1 << d4shift) - 1);
    const int slot = threadIdx.x >> d4shift;
    const int spb = 256 >> d4shift;
    const int t = totals[b] + blockIdx.x * spb + slot;
    if (t >= T) return;
    f32x4 z = {0.f, 0.f, 0.f, 0.f};
    __builtin_nontemporal_store(z, &out4[(((long long)(b * T + t)) << d4shift) + lane]);
}

extern "C" void kernel_launch(void* const* d_in, const int* in_sizes, int n_in,
                              void* d_out, int out_size, void* d_ws, size_t ws_size,
                              hipStream_t stream) {
    const float* x = (const float*)d_in[0];
    const float* dur = (const float*)d_in[1];
    const unsigned int* scale = (const unsigned int*)d_in[2];

    const int B = BATCH;
    const int D = in_sizes[0] / in_sizes[1];   // 512
    const int S = in_sizes[1] / B;             // 1024
    const int T = (out_size - B) / (B * D);    // batch-max total length

    float* out = (float*)d_out;
    float* out_tail = out + (long long)B * T * D;

    int* starts = (int*)d_ws;                  // B*S ints
    int* totals = starts + (long long)B * S;   // B ints

    lr_scan_kernel<<<B, 256, 0, stream>>>(dur, scale, out_tail, totals, starts, S);

    const int D4 = D / 4;                      // 128, power of two
    int d4shift = 0;
    while ((1 << d4shift) < D4) ++d4shift;     // 7
    const int spb = 256 >> d4shift;            // 2 frame-slots per block

    dim3 egrid(S / (spb * ROWS), B);           // each block covers spb*ROWS source rows
    lr_expand_kernel<<<egrid, 256, 0, stream>>>((const f32x4*)x, starts, totals,
                                                (f32x4*)out, S, T, d4shift);

    dim3 zgrid((T + spb - 1) / spb, B);        // worst-case tail coverage, early exit
    lr_zero_tail_kernel<<<zgrid, 256, 0, stream>>>(totals, (f32x4*)out, T, d4shift);
}

// Round 7
// 305.985 us; speedup vs baseline: 1.0370x; 1.0370x over previous
//
#include <hip/hip_runtime.h>

#define BATCH 32

typedef float f32x4 __attribute__((ext_vector_type(4)));

// Kernel 1: per-row duration scan + inverse-index scatter + totals.
// One block (256 threads) per batch row; each thread owns S/256 consecutive
// source positions. idxmap is only B*T ints (~475 KB) — trivial traffic.
__global__ void lr_scan_kernel(const float* __restrict__ dur,
                               const unsigned int* __restrict__ scale_raw,
                               float* __restrict__ out_tail,   // B floats (total_lengths, output 1)
                               int* __restrict__ totals,       // B ints (workspace)
                               int* __restrict__ idxmap,       // B*T ints (workspace)
                               int S, int T) {
    __shared__ int partial[256];
    const int b = blockIdx.x;
    const int tid = threadIdx.x;

    // duration_scale dtype is ambiguous (python scalar). Normal floats have
    // exponent bits set => raw >= 0x00800000; small ints don't.
    unsigned int u = scale_raw[0];
    float scale = (u < 0x00800000u) ? (float)(int)u : __uint_as_float(u);

    const int PER = S / 256;            // 4 for S=1024
    int d[8];                           // supports S up to 2048
    int lsum = 0;
    const int base = tid * PER;
    for (int k = 0; k < PER; ++k) {
        float f = dur[b * S + base + k];
        int di = (int)(f * scale + 0.5f);   // trunc of non-negative == round-half-up
        if (di < 1) di = 1;
        d[k] = di;
        lsum += di;
    }
    partial[tid] = lsum;
    __syncthreads();

    // Hillis-Steele inclusive scan over 256 per-thread sums
    for (int off = 1; off < 256; off <<= 1) {
        int t = (tid >= off) ? partial[tid - off] : 0;
        __syncthreads();
        partial[tid] += t;
        __syncthreads();
    }

    int run = partial[tid] - lsum;      // exclusive prefix = start of this thread's span
    for (int k = 0; k < PER; ++k) {
        int e = run + d[k];
        for (int j = run; j < e; ++j)
            idxmap[b * T + j] = base + k;
        run = e;
    }

    if (tid == 255) {
        int total = partial[255];
        totals[b] = total;
        out_tail[b] = (float)total;     // output dtype for the flat buffer is f32
    }
}

// Kernel 2: 2D grid — blockIdx.y = batch, each 256-thread block covers
// 256>>d4shift output frames. All index math is shifts/masks (no division).
// Nontemporal stores keep x resident in L2/L3 for the gather re-reads.
// Measured-best structure (R4: 307.2 µs); FPB=16 batching (R5) and
// expansion-scatter (R6) were neutral/regressive — window is dominated by
// ~200 µs of harness re-poison traffic at 80-83% HBM peak.
__global__ __launch_bounds__(256) void lr_fill_kernel(
        const f32x4* __restrict__ x4,
        const int* __restrict__ idxmap,
        const int* __restrict__ totals,
        f32x4* __restrict__ out4,
        int S, int T, int d4shift) {
    const int b = blockIdx.y;
    const int D4m1 = (1 << d4shift) - 1;
    const int lane = threadIdx.x & D4m1;
    const int fpb = 256 >> d4shift;                       // frames per block
    const int t = blockIdx.x * fpb + (threadIdx.x >> d4shift);
    if (t >= T) return;

    f32x4 v = (f32x4)(0.f, 0.f, 0.f, 0.f);
    if (t < totals[b]) {
        const int s = idxmap[b * T + t];                  // broadcast within wave
        v = x4[(((long long)(b * S + s)) << d4shift) + lane];
    }
    __builtin_nontemporal_store(v, &out4[(((long long)(b * T + t)) << d4shift) + lane]);
}

extern "C" void kernel_launch(void* const* d_in, const int* in_sizes, int n_in,
                              void* d_out, int out_size, void* d_ws, size_t ws_size,
                              hipStream_t stream) {
    const float* x = (const float*)d_in[0];
    const float* dur = (const float*)d_in[1];
    const unsigned int* scale = (const unsigned int*)d_in[2];

    const int B = BATCH;
    const int D = in_sizes[0] / in_sizes[1];   // 512
    const int S = in_sizes[1] / B;             // 1024
    const int T = (out_size - B) / (B * D);    // batch-max total length

    float* out = (float*)d_out;
    float* out_tail = out + (long long)B * T * D;

    int* idxmap = (int*)d_ws;                  // B*T ints
    int* totals = idxmap + (long long)B * T;   // B ints

    lr_scan_kernel<<<B, 256, 0, stream>>>(dur, scale, out_tail, totals, idxmap, S, T);

    const int D4 = D / 4;                      // 128, power of two
    int d4shift = 0;
    while ((1 << d4shift) < D4) ++d4shift;     // 7
    const int fpb = 256 >> d4shift;            // frames per 256-thread block
    dim3 grid((T + fpb - 1) / fpb, B);
    lr_fill_kernel<<<grid, 256, 0, stream>>>((const f32x4*)x, idxmap, totals,
                                             (f32x4*)out, S, T, d4shift);
}